// Round 7
// baseline (418.540 us; speedup 1.0000x reference)
//
#include <hip/hip_runtime.h>
#include <hip/hip_bf16.h>

#define KK 9
#define PADK 4
#define CIN 64
#define COUT 64
#define LSEQ 131072
#define NB 4
#define TILEL 128         // l-extent of a block tile (>=128B wave row segment, R2 lesson)
#define XROWS 136         // TILEL + KK - 1
#define XRS 72            // xt row stride (bf16); 144 B rows -> uniform 8/bank reads
#define NTILES 1024       // LSEQ / TILEL
#define NPART 64
#define TPB 2             // tiles per block: prefetch pipeline (R1 lesson, now at 5 waves/EU)
#define GRIDC (NB * NTILES / TPB)   // 2048 blocks

typedef __attribute__((ext_vector_type(8))) short v8s;
typedef __attribute__((ext_vector_type(4))) float v4f;

__device__ __forceinline__ unsigned short f2bf(float f) {
  __hip_bfloat16 h = __float2bfloat16(f);
  return *reinterpret_cast<unsigned short*>(&h);
}
__device__ __forceinline__ float bf2f(unsigned short s) {
  return __uint_as_float(((unsigned)s) << 16);
}

__device__ __forceinline__ void store_o(float* p, float v) { *p = v; }
__device__ __forceinline__ void store_o(__hip_bfloat16* p, float v) { *p = __float2bfloat16(v); }

// 16-lane (intra-row) sum on the VALU pipe via DPP (verified R2/R4/R6)
template <int CTRL>
__device__ __forceinline__ float dppadd(float v) {
  int s = __builtin_amdgcn_update_dpp(0, __float_as_int(v), CTRL, 0xF, 0xF, true);
  return v + __int_as_float(s);
}
__device__ __forceinline__ float red16(float v) {
  v = dppadd<0xB1>(v);    // quad_perm xor1
  v = dppadd<0x4E>(v);    // quad_perm xor2
  v = dppadd<0x141>(v);   // row_half_mirror (xor 4)
  v = dppadd<0x140>(v);   // row_mirror (xor 8)
  return v;
}

// ---------------------------------------------------------------------------
// Repack W[Cout][Cin][K] fp32 -> bf16 A-fragments for mfma_f32_16x16x32_bf16,
// pre-swizzled: frag (k, s, mblk) is 1024 contiguous bytes, lane-major.
// ---------------------------------------------------------------------------
__global__ void wtrans_kernel(const float* __restrict__ W, v8s* __restrict__ Wt) {
  int t = blockIdx.x * 256 + threadIdx.x;
  if (t >= KK * 2 * 4 * 64) return;
  int lane = t & 63;
  int frag = t >> 6;
  int mblk = frag & 3;
  int s    = (frag >> 2) & 1;
  int k    = frag >> 3;
  int m = lane & 15, q = lane >> 4;
  int o = mblk * 16 + m;
  union { v8s v; unsigned short h[8]; } u;
#pragma unroll
  for (int j = 0; j < 8; ++j) {
    int c = 32 * s + q * 8 + j;
    u.h[j] = f2bf(W[(o * CIN + c) * KK + k]);
  }
  Wt[t] = u.v;
}

// ---------------------------------------------------------------------------
// R7 conv: R6's register-slim direct-accumulation body (40 VGPR, 5 waves/EU)
// + R1/R4's issue-early prefetch pipeline (TPB=2, single LDS buffer):
//   stage t0 | issue t1 loads | lgkm-barrier (loads in flight) | MFMA t0 |
//   barrier | epilogue t0 / stage t1 (loads landed under compute) | ...
// R6 proved occupancy alone is not the lever (40->58% occ, 116->114us);
// R1 proved the pipeline gains ~26%/tile when residency survives. Here both.
// ---------------------------------------------------------------------------
template <typename OutT>
__global__ __launch_bounds__(256, 5)
void conv_kernel(const float* __restrict__ x, const float* __restrict__ coords,
                 const v8s* __restrict__ Wt, OutT* __restrict__ cv,
                 float* __restrict__ stat_sum, float* __restrict__ stat_sq) {
  __shared__ __align__(16) __hip_bfloat16 xt[XROWS][XRS]; // 19584 B
  __shared__ float wt[KK][TILEL];                         //  4608 B (raw w)

  const int tid  = threadIdx.x;
  const int wv   = tid >> 6;
  const int wo   = wv & 1;                    // o-half (32 rows)
  const int wl   = wv >> 1;                   // l-half (64 cols)
  const int lane = tid & 63;
  const int m = lane & 15;
  const int q = lane >> 4;

  const int bid = blockIdx.x;                 // 0..2047
  const int b   = bid >> 9;                   // 512 blocks per batch
  const int t0  = (bid & 511) * TPB;          // 2 consecutive tiles
  const float* xb = x + (b * CIN) * LSEQ;
  const float* cb = coords + (b * 3) * LSEQ;
  OutT* outb = cv + (size_t)(b * COUT) * LSEQ;

  // staging roles
  const int cg8 = tid & 7, lc = tid >> 3, c8 = cg8 * 8;  // x main stage
  const int cn = tid & 127, kh = tid >> 7, k0 = kh * 4;  // coords: kh=0 -> k0..3, kh=1 -> k4..8
  const int nk = kh ? 5 : 4;

  // prefetch registers (live across the compute phase): ~54 regs
  float4 f[8];                                // x main: 8 channels x 4 l
  float4 hx;                                  // halo (tid<128)
  float sx, sy, sz;                           // center coords
  float nx[5], ny[5], nz[5];                  // neighbor coords

  auto prefetch = [&](int tile) {
    const int l0 = tile * TILEL;
#pragma unroll
    for (int t = 0; t < 8; ++t)
      f[t] = *(const float4*)(xb + (c8 + t) * LSEQ + l0 + 4 * lc);
    if (tid < 128) {
      int side = tid >> 6, c = tid & 63;
      hx = make_float4(0.f, 0.f, 0.f, 0.f);
      if (side == 0) {
        if (tile != 0) hx = *(const float4*)(xb + c * LSEQ + l0 - 4);
      } else {
        if (tile != NTILES - 1) hx = *(const float4*)(xb + c * LSEQ + l0 + TILEL);
      }
    }
    sx = cb[l0 + cn];
    sy = cb[LSEQ + l0 + cn];
    sz = cb[2 * LSEQ + l0 + cn];
#pragma unroll
    for (int i = 0; i < 5; ++i) {
      int l = l0 + cn + (k0 + i) - PADK;
      float cx = 0.f, cy = 0.f, cz = 0.f;
      if (i < nk && (unsigned)l < (unsigned)LSEQ) {   // zero-pad like jnp.pad
        cx = cb[l]; cy = cb[LSEQ + l]; cz = cb[2 * LSEQ + l];
      }
      nx[i] = cx; ny[i] = cy; nz[i] = cz;
    }
  };

  prefetch(t0);

#pragma unroll 1
  for (int ti = 0; ti < TPB; ++ti) {
    const int tile = t0 + ti;
    const int l0 = tile * TILEL;

    // ---- consume prefetched regs -> LDS (xt protected by prev iter's
    //      post-compute barrier) ----
    {
      const float* fp = (const float*)&f[0];
#pragma unroll
      for (int j = 0; j < 4; ++j) {
        union { v8s v; unsigned short h[8]; } u;
#pragma unroll
        for (int t = 0; t < 8; ++t) u.h[t] = f2bf(fp[4 * t + j]);
        *(v8s*)&xt[4 + 4 * lc + j][c8] = u.v;
      }
      if (tid < 128) {
        int side = tid >> 6, c = tid & 63;
        int rb = side ? (TILEL + PADK) : 0;
        xt[rb + 0][c] = __float2bfloat16(hx.x);
        xt[rb + 1][c] = __float2bfloat16(hx.y);
        xt[rb + 2][c] = __float2bfloat16(hx.z);
        xt[rb + 3][c] = __float2bfloat16(hx.w);
      }
      // gaussian weights (raw; direct accumulation uses w_k)
#pragma unroll
      for (int i = 0; i < 5; ++i) {
        if (i < nk) {
          float dx = nx[i] - sx, dy = ny[i] - sy, dz = nz[i] - sz;
          wt[k0 + i][cn] = __expf(-0.5f * (dx * dx + dy * dy + dz * dz));
        }
      }
    }

    // ---- issue next tile's global loads; they stay in flight across the
    //      raw barrier (lgkm-only drain) and land under the MFMA phase ----
    if (ti + 1 < TPB) prefetch(tile + 1);

    asm volatile("s_waitcnt lgkmcnt(0)" ::: "memory");
    __builtin_amdgcn_s_barrier();

    // ---- MFMA main loop: direct per-k weighted accumulation (R6 body) ----
    v4f tot[2][4];
#pragma unroll
    for (int i = 0; i < 2; ++i)
#pragma unroll
      for (int j = 0; j < 4; ++j)
        tot[i][j] = (v4f){0.f, 0.f, 0.f, 0.f};

    const v4f z4 = (v4f){0.f, 0.f, 0.f, 0.f};
    const v8s* wp = Wt + (wo * 2) * 64 + lane;   // frag(k,s,mb) @ k*512+s*256+mb*64

#pragma unroll 1
    for (int k = 0; k < KK; ++k) {
      v8s a00 = wp[k * 512];              // s=0, mb=0
      v8s a10 = wp[k * 512 + 64];         // s=0, mb=1
      v8s a01 = wp[k * 512 + 256];        // s=1, mb=0
      v8s a11 = wp[k * 512 + 256 + 64];   // s=1, mb=1
#pragma unroll
      for (int nbq = 0; nbq < 4; ++nbq) {
        const __hip_bfloat16* xr = &xt[wl * 64 + nbq * 16 + m + k][0];
        v8s bf0 = *(const v8s*)(xr + q * 8);
        v8s bf1 = *(const v8s*)(xr + q * 8 + 32);
        float wk = wt[k][wl * 64 + nbq * 16 + m];
        v4f y0 = __builtin_amdgcn_mfma_f32_16x16x32_bf16(a00, bf0, z4, 0, 0, 0);
        y0     = __builtin_amdgcn_mfma_f32_16x16x32_bf16(a01, bf1, y0, 0, 0, 0);
        v4f y1 = __builtin_amdgcn_mfma_f32_16x16x32_bf16(a10, bf0, z4, 0, 0, 0);
        y1     = __builtin_amdgcn_mfma_f32_16x16x32_bf16(a11, bf1, y1, 0, 0, 0);
#pragma unroll
        for (int r = 0; r < 4; ++r) {
          tot[0][nbq][r] = __builtin_fmaf(wk, y0[r], tot[0][nbq][r]);
          tot[1][nbq][r] = __builtin_fmaf(wk, y1[r], tot[1][nbq][r]);
        }
      }
    }

    // ---- all waves done reading xt/wt: next iter's staging may proceed
    //      while this wave runs its epilogue ----
    __builtin_amdgcn_s_barrier();

    // ---- epilogue: store conv result + per-channel sum/sumsq partials ----
    const int part = tile & (NPART - 1);
#pragma unroll
    for (int mb = 0; mb < 2; ++mb) {
#pragma unroll
      for (int r = 0; r < 4; ++r) {
        int o = wo * 32 + mb * 16 + q * 4 + r;   // C-layout: row = q*4 + reg
        float s1 = 0.f, s2 = 0.f;
#pragma unroll
        for (int nbq = 0; nbq < 4; ++nbq) {
          float v = tot[mb][nbq][r];
          s1 += v;
          s2 += v * v;
          store_o(&outb[o * LSEQ + l0 + wl * 64 + nbq * 16 + m], v); // col = lane&15
        }
        s1 = red16(s1);                          // VALU-pipe DPP reduction
        s2 = red16(s2);
        if (m == 0) {
          atomicAdd(&stat_sum[part * COUT + o], s1);
          atomicAdd(&stat_sq [part * COUT + o], s2);
        }
      }
    }
  }
}

// ---------------------------------------------------------------------------
// BN finalize: scale = gamma*rsqrt(var+eps), shift = beta - mean*scale.
// 256 threads (o x 4 part-quarters).
// ---------------------------------------------------------------------------
__global__ __launch_bounds__(256)
void finalize_kernel(const float* __restrict__ stat_sum,
                     const float* __restrict__ stat_sq,
                     const float* __restrict__ gamma,
                     const float* __restrict__ beta,
                     float* __restrict__ ss) {
  __shared__ float red[2][4][COUT];
  const int o = threadIdx.x & 63, pq = threadIdx.x >> 6;
  float s1 = 0.f, s2 = 0.f;
#pragma unroll 4
  for (int p = pq * 16; p < pq * 16 + 16; ++p) {
    s1 += stat_sum[p * COUT + o];
    s2 += stat_sq [p * COUT + o];
  }
  red[0][pq][o] = s1;
  red[1][pq][o] = s2;
  __syncthreads();
  if (threadIdx.x < 64) {
    float t1 = red[0][0][o] + red[0][1][o] + red[0][2][o] + red[0][3][o];
    float t2 = red[1][0][o] + red[1][1][o] + red[1][2][o] + red[1][3][o];
    const float invN = 1.0f / (float)(NB * LSEQ);
    float mean = t1 * invN;
    float var  = t2 * invN - mean * mean;   // biased, matches jnp.var
    float sc = gamma[o] * rsqrtf(var + 1e-5f);
    ss[o]        = sc;
    ss[COUT + o] = beta[o] - mean * sc;
  }
}

// ---- BN apply + ReLU; one block = 2048 contiguous elems in one channel ----
__global__ __launch_bounds__(256)
void scale_f32_kernel(float* __restrict__ data, const float* __restrict__ ss) {
  const int blk = blockIdx.x;
  const int ch = (blk >> 6) & 63;   // L/2048 = 64 blocks per channel
  const float sc = ss[ch];
  const float sh = ss[COUT + ch];
  const int base = blk * 2048 + threadIdx.x * 8;
  float4 a = *(float4*)(data + base);
  float4 b = *(float4*)(data + base + 4);
  a.x = fmaxf(fmaf(a.x, sc, sh), 0.f);
  a.y = fmaxf(fmaf(a.y, sc, sh), 0.f);
  a.z = fmaxf(fmaf(a.z, sc, sh), 0.f);
  a.w = fmaxf(fmaf(a.w, sc, sh), 0.f);
  b.x = fmaxf(fmaf(b.x, sc, sh), 0.f);
  b.y = fmaxf(fmaf(b.y, sc, sh), 0.f);
  b.z = fmaxf(fmaf(b.z, sc, sh), 0.f);
  b.w = fmaxf(fmaf(b.w, sc, sh), 0.f);
  *(float4*)(data + base)     = a;
  *(float4*)(data + base + 4) = b;
}

__global__ __launch_bounds__(256)
void scale_bf16_kernel(const __hip_bfloat16* __restrict__ cvin,
                       const float* __restrict__ ss, float* __restrict__ out) {
  const int blk = blockIdx.x;
  const int ch = (blk >> 6) & 63;
  const float sc = ss[ch];
  const float sh = ss[COUT + ch];
  const int base = blk * 2048 + threadIdx.x * 8;
  union { v8s v; unsigned short h[8]; } u;
  u.v = *(const v8s*)(cvin + base);
  float r[8];
#pragma unroll
  for (int i = 0; i < 8; ++i)
    r[i] = fmaxf(fmaf(bf2f(u.h[i]), sc, sh), 0.f);
  *(float4*)(out + base)     = make_float4(r[0], r[1], r[2], r[3]);
  *(float4*)(out + base + 4) = make_float4(r[4], r[5], r[6], r[7]);
}

extern "C" void kernel_launch(void* const* d_in, const int* in_sizes, int n_in,
                              void* d_out, int out_size, void* d_ws, size_t ws_size,
                              hipStream_t stream) {
  const float* x      = (const float*)d_in[0];
  const float* coords = (const float*)d_in[1];
  const float* W      = (const float*)d_in[2];
  // d_in[3] = bias: cancels under training-mode BatchNorm; unused.
  const float* gamma  = (const float*)d_in[4];
  const float* beta   = (const float*)d_in[5];
  float* out = (float*)d_out;
  char* ws = (char*)d_ws;

  float* stat_sum = (float*)(ws);            // 64*64 f32
  float* stat_sq  = (float*)(ws + 16384);    // 64*64 f32
  float* ss       = (float*)(ws + 32768);    // 128 f32
  v8s*   Wt       = (v8s*)(ws + 40960);      // 73728 B
  __hip_bfloat16* scratch = (__hip_bfloat16*)(ws + 131072); // 64 MiB (optional)

  const size_t need_bf16 = (size_t)131072 + (size_t)NB * COUT * LSEQ * 2;
  const bool bf16_path = ws_size >= need_bf16;

  hipMemsetAsync(ws, 0, 32768, stream);
  wtrans_kernel<<<18, 256, 0, stream>>>(W, Wt);

  if (bf16_path) {
    conv_kernel<__hip_bfloat16><<<GRIDC, 256, 0, stream>>>(
        x, coords, Wt, scratch, stat_sum, stat_sq);
    finalize_kernel<<<1, 256, 0, stream>>>(stat_sum, stat_sq, gamma, beta, ss);
    scale_bf16_kernel<<<(NB * COUT * (LSEQ / 2048)), 256, 0, stream>>>(scratch, ss, out);
  } else {
    conv_kernel<float><<<GRIDC, 256, 0, stream>>>(
        x, coords, Wt, out, stat_sum, stat_sq);
    finalize_kernel<<<1, 256, 0, stream>>>(stat_sum, stat_sq, gamma, beta, ss);
    scale_f32_kernel<<<(NB * COUT * (LSEQ / 2048)), 256, 0, stream>>>(out, ss);
  }
}

// Round 8
// 320.462 us; speedup vs baseline: 1.3061x; 1.3061x over previous
//
#include <hip/hip_runtime.h>
#include <hip/hip_bf16.h>

#define KK 9
#define PADK 4
#define CIN 64
#define COUT 64
#define LSEQ 131072
#define NB 4
#define TILEL 128         // l-extent of a block tile (>=128B wave row segment, R2 lesson)
#define XROWS 136         // TILEL + KK - 1
#define XRS 72            // xt row stride (bf16); 144 B rows -> uniform 8/bank reads
#define NTILES 1024       // LSEQ / TILEL
#define NPART 64

typedef __attribute__((ext_vector_type(8))) short v8s;
typedef __attribute__((ext_vector_type(4))) float v4f;

__device__ __forceinline__ unsigned short f2bf(float f) {
  __hip_bfloat16 h = __float2bfloat16(f);
  return *reinterpret_cast<unsigned short*>(&h);
}
__device__ __forceinline__ float bf2f(unsigned short s) {
  return __uint_as_float(((unsigned)s) << 16);
}

__device__ __forceinline__ void store_o(float* p, float v) { *p = v; }
__device__ __forceinline__ void store_o(__hip_bfloat16* p, float v) { *p = __float2bfloat16(v); }

// 16-lane (intra-row) sum on the VALU pipe via DPP (verified R2/R4/R6)
template <int CTRL>
__device__ __forceinline__ float dppadd(float v) {
  int s = __builtin_amdgcn_update_dpp(0, __float_as_int(v), CTRL, 0xF, 0xF, true);
  return v + __int_as_float(s);
}
__device__ __forceinline__ float red16(float v) {
  v = dppadd<0xB1>(v);    // quad_perm xor1
  v = dppadd<0x4E>(v);    // quad_perm xor2
  v = dppadd<0x141>(v);   // row_half_mirror (xor 4)
  v = dppadd<0x140>(v);   // row_mirror (xor 8)
  return v;
}

// ---------------------------------------------------------------------------
// Repack W[Cout][Cin][K] fp32 -> bf16 A-fragments for mfma_f32_16x16x32_bf16,
// pre-swizzled: frag (k, s, mblk) is 1024 contiguous bytes, lane-major.
// ---------------------------------------------------------------------------
__global__ void wtrans_kernel(const float* __restrict__ W, v8s* __restrict__ Wt) {
  int t = blockIdx.x * 256 + threadIdx.x;
  if (t >= KK * 2 * 4 * 64) return;
  int lane = t & 63;
  int frag = t >> 6;
  int mblk = frag & 3;
  int s    = (frag >> 2) & 1;
  int k    = frag >> 3;
  int m = lane & 15, q = lane >> 4;
  int o = mblk * 16 + m;
  union { v8s v; unsigned short h[8]; } u;
#pragma unroll
  for (int j = 0; j < 8; ++j) {
    int c = 32 * s + q * 8 + j;
    u.h[j] = f2bf(W[(o * CIN + c) * KK + k]);
  }
  Wt[t] = u.v;
}

// ---------------------------------------------------------------------------
// Weighted conv via MFMA. R8 = R6 (register-slim direct accumulation, 5
// waves/EU) + one-k-ahead register prefetch of the 4 A-fragments ONLY
// (16 extra VGPRs, ~88 unified total <= 102 cap -> no spill; R7's whole-tile
// prefetch at ~126 regs spilled to scratch and tripled HBM traffic).
// The k+1 loads issue before k's 16-MFMA cluster, hiding L1/L2 latency.
// ---------------------------------------------------------------------------
template <typename OutT>
__global__ __launch_bounds__(256, 5)
void conv_kernel(const float* __restrict__ x, const float* __restrict__ coords,
                 const v8s* __restrict__ Wt, OutT* __restrict__ cv,
                 float* __restrict__ stat_sum, float* __restrict__ stat_sq) {
  __shared__ __align__(16) __hip_bfloat16 xt[XROWS][XRS]; // 19584 B
  __shared__ float wt[KK][TILEL];                         //  4608 B (raw w)

  const int tid  = threadIdx.x;
  const int wv   = tid >> 6;
  const int wo   = wv & 1;                    // o-half (32 rows)
  const int wl   = wv >> 1;                   // l-half (64 cols)
  const int lane = tid & 63;
  const int gw   = blockIdx.x;                // tile id, 0..4095
  const int b    = gw >> 10;                  // / NTILES
  const int tile = gw & (NTILES - 1);
  const int l0   = tile * TILEL;
  const float* xb = x + (b * CIN) * LSEQ;
  const float* cb = coords + (b * 3) * LSEQ;
  const int m = lane & 15;
  const int q = lane >> 4;

  // ---- stage main x region (rows 4..131): lane-inner = channel-group so each
  //      b128 LDS write covers all 32 banks uniformly ----
  {
    int cg = tid & 7;                         // channel group (8 ch each)
    int lc = tid >> 3;                        // l-chunk 0..31 (4 l each)
    int c8 = cg * 8;
    float4 f[8];
#pragma unroll
    for (int t = 0; t < 8; ++t)
      f[t] = *(const float4*)(xb + (c8 + t) * LSEQ + l0 + 4 * lc);
    const float* fp = (const float*)&f[0];
#pragma unroll
    for (int j = 0; j < 4; ++j) {
      union { v8s v; unsigned short h[8]; } u;
#pragma unroll
      for (int t = 0; t < 8; ++t) u.h[t] = f2bf(fp[4 * t + j]);
      *(v8s*)&xt[4 + 4 * lc + j][c8] = u.v;
    }
  }
  // ---- halos (rows 0..3 and 132..135), zero-padded at sequence ends ----
  if (tid < 128) {
    int side = tid >> 6;
    int c = tid & 63;
    if (side == 0) {
      float el[4] = {0.f, 0.f, 0.f, 0.f};
      if (tile != 0) {
#pragma unroll
        for (int j = 0; j < 4; ++j) el[j] = xb[c * LSEQ + l0 - 4 + j];
      }
#pragma unroll
      for (int j = 0; j < 4; ++j) xt[j][c] = __float2bfloat16(el[j]);
    } else {
      float er[4] = {0.f, 0.f, 0.f, 0.f};
      if (tile != NTILES - 1) {
#pragma unroll
        for (int j = 0; j < 4; ++j) er[j] = xb[c * LSEQ + l0 + TILEL + j];
      }
#pragma unroll
      for (int j = 0; j < 4; ++j) xt[128 + 4 + j][c] = __float2bfloat16(er[j]);
    }
  }
  // ---- gaussian weights (raw; direct accumulation needs w_k) ----
  if (tid < TILEL) {
    int n = tid;
    float sx = cb[l0 + n];
    float sy = cb[LSEQ + l0 + n];
    float sz = cb[2 * LSEQ + l0 + n];
#pragma unroll
    for (int k = 0; k < KK; ++k) {
      int l = l0 + n + k - PADK;
      float cx = 0.f, cy = 0.f, cz = 0.f;
      if ((unsigned)l < (unsigned)LSEQ) {     // zero-pad like jnp.pad
        cx = cb[l]; cy = cb[LSEQ + l]; cz = cb[2 * LSEQ + l];
      }
      float dx = cx - sx, dy = cy - sy, dz = cz - sz;
      wt[k][n] = __expf(-0.5f * (dx * dx + dy * dy + dz * dz));
    }
  }
  __syncthreads();

  // ---- MFMA main loop: direct per-k weighted accumulation, with the next
  //      k's A-fragments loaded into registers before this k's MFMA cluster ----
  v4f tot[2][4];
#pragma unroll
  for (int i = 0; i < 2; ++i)
#pragma unroll
    for (int j = 0; j < 4; ++j)
      tot[i][j] = (v4f){0.f, 0.f, 0.f, 0.f};

  const v4f z4 = (v4f){0.f, 0.f, 0.f, 0.f};
  // frag(k,s,mb) at Wt[k*512 + s*256 + mb*64 + lane]
  const v8s* wp = Wt + (wo * 2) * 64 + lane;

  v8s a00 = wp[0];          // k=0: s=0, mb=0
  v8s a10 = wp[64];         //      s=0, mb=1
  v8s a01 = wp[256];        //      s=1, mb=0
  v8s a11 = wp[320];        //      s=1, mb=1

#pragma unroll 1
  for (int k = 0; k < KK; ++k) {
    // issue k+1's fragment loads now; they complete under the MFMA cluster
    const int kn = (k + 1 < KK) ? k + 1 : 0;   // harmless reload of k=0 on last
    const v8s* wn = wp + kn * 512;
    v8s b00 = wn[0];
    v8s b10 = wn[64];
    v8s b01 = wn[256];
    v8s b11 = wn[320];
#pragma unroll
    for (int nbq = 0; nbq < 4; ++nbq) {
      const __hip_bfloat16* xr = &xt[wl * 64 + nbq * 16 + m + k][0];
      v8s bf0 = *(const v8s*)(xr + q * 8);
      v8s bf1 = *(const v8s*)(xr + q * 8 + 32);
      float wk = wt[k][wl * 64 + nbq * 16 + m];
      v4f y0 = __builtin_amdgcn_mfma_f32_16x16x32_bf16(a00, bf0, z4, 0, 0, 0);
      y0     = __builtin_amdgcn_mfma_f32_16x16x32_bf16(a01, bf1, y0, 0, 0, 0);
      v4f y1 = __builtin_amdgcn_mfma_f32_16x16x32_bf16(a10, bf0, z4, 0, 0, 0);
      y1     = __builtin_amdgcn_mfma_f32_16x16x32_bf16(a11, bf1, y1, 0, 0, 0);
#pragma unroll
      for (int r = 0; r < 4; ++r) {
        tot[0][nbq][r] = __builtin_fmaf(wk, y0[r], tot[0][nbq][r]);
        tot[1][nbq][r] = __builtin_fmaf(wk, y1[r], tot[1][nbq][r]);
      }
    }
    a00 = b00; a10 = b10; a01 = b01; a11 = b11;   // rotate (register rename)
  }

  // ---- epilogue: store conv result + per-channel sum/sumsq partials ----
  const int part = gw & (NPART - 1);
  OutT* outb = cv + (size_t)(b * COUT) * LSEQ;
#pragma unroll
  for (int mb = 0; mb < 2; ++mb) {
#pragma unroll
    for (int r = 0; r < 4; ++r) {
      int o = wo * 32 + mb * 16 + q * 4 + r;   // C-layout: row = q*4 + reg
      float s1 = 0.f, s2 = 0.f;
#pragma unroll
      for (int nbq = 0; nbq < 4; ++nbq) {
        float v = tot[mb][nbq][r];
        s1 += v;
        s2 += v * v;
        store_o(&outb[o * LSEQ + l0 + wl * 64 + nbq * 16 + m], v); // col = lane&15
      }
      s1 = red16(s1);                          // VALU-pipe DPP reduction
      s2 = red16(s2);
      if (m == 0) {
        atomicAdd(&stat_sum[part * COUT + o], s1);
        atomicAdd(&stat_sq [part * COUT + o], s2);
      }
    }
  }
}

// ---------------------------------------------------------------------------
// BN finalize: scale = gamma*rsqrt(var+eps), shift = beta - mean*scale.
// 256 threads (o x 4 part-quarters).
// ---------------------------------------------------------------------------
__global__ __launch_bounds__(256)
void finalize_kernel(const float* __restrict__ stat_sum,
                     const float* __restrict__ stat_sq,
                     const float* __restrict__ gamma,
                     const float* __restrict__ beta,
                     float* __restrict__ ss) {
  __shared__ float red[2][4][COUT];
  const int o = threadIdx.x & 63, pq = threadIdx.x >> 6;
  float s1 = 0.f, s2 = 0.f;
#pragma unroll 4
  for (int p = pq * 16; p < pq * 16 + 16; ++p) {
    s1 += stat_sum[p * COUT + o];
    s2 += stat_sq [p * COUT + o];
  }
  red[0][pq][o] = s1;
  red[1][pq][o] = s2;
  __syncthreads();
  if (threadIdx.x < 64) {
    float t1 = red[0][0][o] + red[0][1][o] + red[0][2][o] + red[0][3][o];
    float t2 = red[1][0][o] + red[1][1][o] + red[1][2][o] + red[1][3][o];
    const float invN = 1.0f / (float)(NB * LSEQ);
    float mean = t1 * invN;
    float var  = t2 * invN - mean * mean;   // biased, matches jnp.var
    float sc = gamma[o] * rsqrtf(var + 1e-5f);
    ss[o]        = sc;
    ss[COUT + o] = beta[o] - mean * sc;
  }
}

// ---- BN apply + ReLU; one block = 2048 contiguous elems in one channel ----
__global__ __launch_bounds__(256)
void scale_f32_kernel(float* __restrict__ data, const float* __restrict__ ss) {
  const int blk = blockIdx.x;
  const int ch = (blk >> 6) & 63;   // L/2048 = 64 blocks per channel
  const float sc = ss[ch];
  const float sh = ss[COUT + ch];
  const int base = blk * 2048 + threadIdx.x * 8;
  float4 a = *(float4*)(data + base);
  float4 b = *(float4*)(data + base + 4);
  a.x = fmaxf(fmaf(a.x, sc, sh), 0.f);
  a.y = fmaxf(fmaf(a.y, sc, sh), 0.f);
  a.z = fmaxf(fmaf(a.z, sc, sh), 0.f);
  a.w = fmaxf(fmaf(a.w, sc, sh), 0.f);
  b.x = fmaxf(fmaf(b.x, sc, sh), 0.f);
  b.y = fmaxf(fmaf(b.y, sc, sh), 0.f);
  b.z = fmaxf(fmaf(b.z, sc, sh), 0.f);
  b.w = fmaxf(fmaf(b.w, sc, sh), 0.f);
  *(float4*)(data + base)     = a;
  *(float4*)(data + base + 4) = b;
}

__global__ __launch_bounds__(256)
void scale_bf16_kernel(const __hip_bfloat16* __restrict__ cvin,
                       const float* __restrict__ ss, float* __restrict__ out) {
  const int blk = blockIdx.x;
  const int ch = (blk >> 6) & 63;
  const float sc = ss[ch];
  const float sh = ss[COUT + ch];
  const int base = blk * 2048 + threadIdx.x * 8;
  union { v8s v; unsigned short h[8]; } u;
  u.v = *(const v8s*)(cvin + base);
  float r[8];
#pragma unroll
  for (int i = 0; i < 8; ++i)
    r[i] = fmaxf(fmaf(bf2f(u.h[i]), sc, sh), 0.f);
  *(float4*)(out + base)     = make_float4(r[0], r[1], r[2], r[3]);
  *(float4*)(out + base + 4) = make_float4(r[4], r[5], r[6], r[7]);
}

extern "C" void kernel_launch(void* const* d_in, const int* in_sizes, int n_in,
                              void* d_out, int out_size, void* d_ws, size_t ws_size,
                              hipStream_t stream) {
  const float* x      = (const float*)d_in[0];
  const float* coords = (const float*)d_in[1];
  const float* W      = (const float*)d_in[2];
  // d_in[3] = bias: cancels under training-mode BatchNorm; unused.
  const float* gamma  = (const float*)d_in[4];
  const float* beta   = (const float*)d_in[5];
  float* out = (float*)d_out;
  char* ws = (char*)d_ws;

  float* stat_sum = (float*)(ws);            // 64*64 f32
  float* stat_sq  = (float*)(ws + 16384);    // 64*64 f32
  float* ss       = (float*)(ws + 32768);    // 128 f32
  v8s*   Wt       = (v8s*)(ws + 40960);      // 73728 B
  __hip_bfloat16* scratch = (__hip_bfloat16*)(ws + 131072); // 64 MiB (optional)

  const size_t need_bf16 = (size_t)131072 + (size_t)NB * COUT * LSEQ * 2;
  const bool bf16_path = ws_size >= need_bf16;

  hipMemsetAsync(ws, 0, 32768, stream);
  wtrans_kernel<<<18, 256, 0, stream>>>(W, Wt);

  if (bf16_path) {
    conv_kernel<__hip_bfloat16><<<NB * NTILES, 256, 0, stream>>>(
        x, coords, Wt, scratch, stat_sum, stat_sq);
    finalize_kernel<<<1, 256, 0, stream>>>(stat_sum, stat_sq, gamma, beta, ss);
    scale_bf16_kernel<<<(NB * COUT * (LSEQ / 2048)), 256, 0, stream>>>(scratch, ss, out);
  } else {
    conv_kernel<float><<<NB * NTILES, 256, 0, stream>>>(
        x, coords, Wt, out, stat_sum, stat_sq);
    finalize_kernel<<<1, 256, 0, stream>>>(stat_sum, stat_sq, gamma, beta, ss);
    scale_f32_kernel<<<(NB * COUT * (LSEQ / 2048)), 256, 0, stream>>>(out, ss);
  }
}